// Round 1
// baseline (379.837 us; speedup 1.0000x reference)
//
#include <hip/hip_runtime.h>

#define DEV __device__ __forceinline__

typedef float f32x4 __attribute__((ext_vector_type(4)));
typedef short short4v __attribute__((ext_vector_type(4)));
typedef short short8v __attribute__((ext_vector_type(8)));
typedef __bf16 bf16x8 __attribute__((ext_vector_type(8)));

DEV unsigned short f2bf(float f) {
  unsigned int u = __float_as_uint(f);
  u += 0x7fffu + ((u >> 16) & 1u);   // round-to-nearest-even
  return (unsigned short)(u >> 16);
}

DEV void async16(void* lds, const void* g) {
  __builtin_amdgcn_global_load_lds((const __attribute__((address_space(1))) void*)g,
                                   (__attribute__((address_space(3))) void*)lds, 16, 0, 0);
}

DEV void store_elem(float* C, long i, float v) { C[i] = v; }
DEV void store_elem(short* C, long i, float v) { C[i] = (short)f2bf(v); }

// ---------------- cast f32 -> bf16 (8 elems/thread) ----------------
__global__ void cast_bf16_kernel(const float* __restrict__ in, short* __restrict__ out) {
  long i = ((long)blockIdx.x * 256 + threadIdx.x) * 8;
  f32x4 a = *(const f32x4*)(in + i);
  f32x4 b = *(const f32x4*)(in + i + 4);
  short8v o;
#pragma unroll
  for (int j = 0; j < 4; ++j) { o[j] = (short)f2bf(a[j]); o[4 + j] = (short)f2bf(b[j]); }
  *(short8v*)(out + i) = o;
}

// ---------------- W [K=1024][N=1024] f32 -> Wt [N][K] bf16 ----------------
__global__ void transpose_cast_kernel(const float* __restrict__ W, short* __restrict__ Wt) {
  __shared__ float t[32][33];
  int n0 = blockIdx.x * 32, k0 = blockIdx.y * 32;
  int tx = threadIdx.x & 31, ty = threadIdx.x >> 5;
#pragma unroll
  for (int r = 0; r < 32; r += 8) t[ty + r][tx] = W[(long)(k0 + ty + r) * 1024 + n0 + tx];
  __syncthreads();
#pragma unroll
  for (int r = 0; r < 32; r += 8)
    Wt[(long)(n0 + ty + r) * 1024 + k0 + tx] = (short)f2bf(t[tx][ty + r]);
}

// ---------------- GEMM: C[M][N] = scale * A[M][K] @ Bt[N][K]^T (+bias) ----------------
// m97 structure: 128x128 tile, BK=32, 4 waves (2x2), 4x4 16x16x32 bf16 MFMA per wave.
// MODE: 0 plain, 1 = only lower+diag 128-tiles (causal scores), 2 = K capped at (bm+1)*128 (PV).
template <typename CT, int MODE>
__global__ __launch_bounds__(256, 2) void gemm_bt(
    const short* __restrict__ A, const short* __restrict__ Bt, CT* __restrict__ C,
    int K, int lda, int ldbt, int ldc,
    long sA, long sBt, long sC,
    const float* __restrict__ bias_m, const float* __restrict__ bias_n, float scale)
{
  const int bn = blockIdx.x, bm = blockIdx.y, bz = blockIdx.z;
  if (MODE == 1 && bn > bm) return;                       // strictly-above-diagonal tile: skip
  const int kend = (MODE == 2) ? min(K, (bm + 1) * 128) : K;

  A += (long)bz * sA;  Bt += (long)bz * sBt;  C += (long)bz * sC;

  __shared__ short As[128 * 32];
  __shared__ short Bs[128 * 32];

  const int tid = threadIdx.x;
  const int wid = tid >> 6, lane = tid & 63;
  const int wm = wid >> 1, wn = wid & 1;
  const int rC = lane >> 2;           // row within 16-row staging chunk
  const int kB = (lane & 3) * 8;      // bf16 col offset within BK=32
  const int fr = lane & 15;
  const int fkB = (lane >> 4) * 16;   // byte offset of this lane's 8-bf16 k-chunk

  const short* Ab = A + (long)bm * 128 * lda;
  const short* Bb = Bt + (long)bn * 128 * ldbt;

  f32x4 acc[4][4] = {};

  for (int kk = 0; kk < kend; kk += 32) {
#pragma unroll
    for (int j = 0; j < 2; ++j) {     // stage A tile: 8 chunks of 16 rows x 32 bf16
      int chunk = j * 4 + wid;
      async16(&As[chunk * 512], Ab + (long)(chunk * 16 + rC) * lda + kk + kB);
    }
#pragma unroll
    for (int j = 0; j < 2; ++j) {     // stage Bt tile
      int chunk = j * 4 + wid;
      async16(&Bs[chunk * 512], Bb + (long)(chunk * 16 + rC) * ldbt + kk + kB);
    }
    __syncthreads();

    bf16x8 af[4], bf_[4];
#pragma unroll
    for (int i = 0; i < 4; ++i)
      af[i] = *(const bf16x8*)((const char*)As + (wm * 64 + i * 16 + fr) * 64 + fkB);
#pragma unroll
    for (int j = 0; j < 4; ++j)
      bf_[j] = *(const bf16x8*)((const char*)Bs + (wn * 64 + j * 16 + fr) * 64 + fkB);
#pragma unroll
    for (int i = 0; i < 4; ++i)
#pragma unroll
      for (int j = 0; j < 4; ++j)
        acc[i][j] = __builtin_amdgcn_mfma_f32_16x16x32_bf16(af[i], bf_[j], acc[i][j], 0, 0, 0);
    __syncthreads();
  }

  const int fq = lane >> 4;
#pragma unroll
  for (int i = 0; i < 4; ++i) {
#pragma unroll
    for (int r = 0; r < 4; ++r) {
      int row = bm * 128 + wm * 64 + i * 16 + fq * 4 + r;
      float bmv = bias_m ? bias_m[row] : 0.f;
#pragma unroll
      for (int j = 0; j < 4; ++j) {
        int col = bn * 128 + wn * 64 + j * 16 + fr;
        float bnv = bias_n ? bias_n[col] : 0.f;
        store_elem(C, (long)row * ldc + col, acc[i][j][r] * scale + bmv + bnv);
      }
    }
  }
}

// ---------------- column softmax (axis = query) over S[bz][q][c], valid q >= c ----------------
__global__ void colstats_partial(const float* __restrict__ S,
                                 float* __restrict__ pmax, float* __restrict__ psum) {
  const int bz = blockIdx.z;
  const int c = blockIdx.x * 256 + threadIdx.x;
  const int q0 = blockIdx.y * 256;
  const float* Sb = S + (long)bz * 4194304;
  float m = -1e30f;
  for (int q = q0; q < q0 + 256; ++q) {
    float v = Sb[(long)q * 2048 + c];
    if (q >= c) m = fmaxf(m, v);
  }
  float s = 0.f;
  if (m > -1e29f) {
    for (int q = q0; q < q0 + 256; ++q) {
      float v = Sb[(long)q * 2048 + c];
      if (q >= c) s += __expf(v - m);
    }
  }
  long idx = ((long)bz * 8 + blockIdx.y) * 2048 + c;
  pmax[idx] = m; psum[idx] = s;
}

__global__ void colstats_combine(const float* __restrict__ pmax, const float* __restrict__ psum,
                                 float* __restrict__ cmax, float* __restrict__ cinv) {
  const int bz = blockIdx.y;
  const int c = blockIdx.x * 256 + threadIdx.x;
  float M = -1e30f;
#pragma unroll
  for (int ch = 0; ch < 8; ++ch) M = fmaxf(M, pmax[((long)bz * 8 + ch) * 2048 + c]);
  float Ssum = 0.f;
#pragma unroll
  for (int ch = 0; ch < 8; ++ch) {
    float m = pmax[((long)bz * 8 + ch) * 2048 + c];
    float s = psum[((long)bz * 8 + ch) * 2048 + c];
    if (m > -1e29f) Ssum += s * __expf(m - M);
  }
  cmax[(long)bz * 2048 + c] = M;
  cinv[(long)bz * 2048 + c] = 1.f / Ssum;
}

// P[bz][q][c] = (q>=c) ? exp(S-M[c])*Rinv[c] : 0, bf16
__global__ void sm_normalize(const float* __restrict__ S, const float* __restrict__ cmax,
                             const float* __restrict__ cinv, short* __restrict__ P) {
  const int bz = blockIdx.y;
  const int q = blockIdx.x;
  const float* Sr = S + ((long)bz * 2048 + q) * 2048;
  short* Pr = P + ((long)bz * 2048 + q) * 2048;
  const float* Mb = cmax + (long)bz * 2048;
  const float* Rb = cinv + (long)bz * 2048;
#pragma unroll
  for (int half = 0; half < 2; ++half) {
    int c = half * 1024 + threadIdx.x * 4;
    f32x4 sv = *(const f32x4*)(Sr + c);
    f32x4 mv = *(const f32x4*)(Mb + c);
    f32x4 rv = *(const f32x4*)(Rb + c);
    short4v o;
#pragma unroll
    for (int j = 0; j < 4; ++j) {
      float p = (q >= c + j) ? __expf(sv[j] - mv[j]) * rv[j] : 0.f;
      o[j] = (short)f2bf(p);
    }
    *(short4v*)(Pr + c) = o;
  }
}

// ---------------- host side ----------------
extern "C" void kernel_launch(void* const* d_in, const int* in_sizes, int n_in,
                              void* d_out, int out_size, void* d_ws, size_t ws_size,
                              hipStream_t stream) {
  const float* x  = (const float*)d_in[0];
  const float* Wq = (const float*)d_in[1];
  const float* bq = (const float*)d_in[2];
  const float* Wk = (const float*)d_in[3];
  const float* bk = (const float*)d_in[4];
  const float* Wv = (const float*)d_in[5];
  const float* bv = (const float*)d_in[6];
  float* out = (float*)d_out;

  const size_t SZ_XB = 8192ull * 1024 * 2;       // x bf16
  const size_t SZ_WT = 1024ull * 1024 * 2;       // one Wt bf16
  const size_t SZ_QB = SZ_XB;                    // Q / K bf16, Vt bf16
  const size_t N_PMAX = 4ull * 8 * 2048;         // floats
  const size_t N_CMAX = 4ull * 2048;
  const size_t SZ_STATS = (N_PMAX * 2 + N_CMAX * 2) * 4;
  const size_t SZ_S1 = 2048ull * 2048 * 4;       // one batch of S (f32)
  const size_t SZ_P1 = 2048ull * 2048 * 2;       // one batch of P (bf16)

  char* p = (char*)d_ws;
  short* xb  = (short*)p; p += SZ_XB;
  short* wqt = (short*)p; p += SZ_WT;
  short* wkt = (short*)p; p += SZ_WT;
  short* wvt = (short*)p; p += SZ_WT;
  short* qb  = (short*)p; p += SZ_QB;
  short* kb  = (short*)p; p += SZ_QB;
  short* vt  = (short*)p; p += SZ_QB;
  float* pmax = (float*)p;
  float* psum = pmax + N_PMAX;
  float* cmax = psum + N_PMAX;
  float* cinv = cmax + N_CMAX;
  p += SZ_STATS;
  size_t fixed = (size_t)(p - (char*)d_ws);
  // all-batch S/P if workspace allows, else per-batch reuse (stream-serialized)
  int nbuf = (ws_size >= fixed + 4 * (SZ_S1 + SZ_P1)) ? 4 : 1;
  float* S = (float*)p; p += (size_t)nbuf * SZ_S1;
  short* P = (short*)p;

  // 1) casts / transposes
  cast_bf16_kernel<<<dim3(4096), dim3(256), 0, stream>>>(x, xb);
  transpose_cast_kernel<<<dim3(32, 32), dim3(256), 0, stream>>>(Wq, wqt);
  transpose_cast_kernel<<<dim3(32, 32), dim3(256), 0, stream>>>(Wk, wkt);
  transpose_cast_kernel<<<dim3(32, 32), dim3(256), 0, stream>>>(Wv, wvt);

  // 2) projections (bf16 out, f32 accum + bias)
  // Q[s][d] : A=xb[8192][1024], Bt=Wqt[1024][1024], bias over N(d)
  gemm_bt<short, 0><<<dim3(8, 64, 1), dim3(256), 0, stream>>>(
      xb, wqt, qb, 1024, 1024, 1024, 1024, 0L, 0L, 0L, nullptr, bq, 1.f);
  gemm_bt<short, 0><<<dim3(8, 64, 1), dim3(256), 0, stream>>>(
      xb, wkt, kb, 1024, 1024, 1024, 1024, 0L, 0L, 0L, nullptr, bk, 1.f);
  // Vt[d][s] : A=Wvt[1024][1024], Bt=xb[8192][1024], bias over M(d)
  gemm_bt<short, 0><<<dim3(64, 8, 1), dim3(256), 0, stream>>>(
      wvt, xb, vt, 1024, 1024, 1024, 8192, 0L, 0L, 0L, bv, nullptr, 1.f);

  const long QSTR = 2048L * 1024;   // per-batch Q/K elements
  const long SSTR = 2048L * 2048;   // per-batch S/P elements
  const long OSTR = 2048L * 1024;   // per-batch out elements

  for (int b0 = 0; b0 < 4; b0 += nbuf) {
    // 3) scores: S[q][k] = Q.K^T/32, lower+diag tiles only
    gemm_bt<float, 1><<<dim3(16, 16, nbuf), dim3(256), 0, stream>>>(
        qb + b0 * QSTR, kb + b0 * QSTR, S, 1024, 1024, 1024, 2048,
        QSTR, QSTR, SSTR, nullptr, nullptr, 0.03125f);
    // 4) column softmax over q (valid q >= c)
    colstats_partial<<<dim3(8, 8, nbuf), dim3(256), 0, stream>>>(S, pmax, psum);
    colstats_combine<<<dim3(8, nbuf), dim3(256), 0, stream>>>(pmax, psum, cmax, cinv);
    sm_normalize<<<dim3(2048, nbuf), dim3(256), 0, stream>>>(S, cmax, cinv, P);
    // 5) attn = P @ V : A=P[2048][2048], Bt=Vt[1024][8192] (+b0*2048), K capped per q-tile
    gemm_bt<float, 2><<<dim3(8, 16, nbuf), dim3(256), 0, stream>>>(
        P, vt + b0 * 2048, out + (long)b0 * OSTR, 2048, 2048, 8192, 1024,
        SSTR, 2048L, OSTR, nullptr, nullptr, 1.f);
  }
}

// Round 2
// 262.061 us; speedup vs baseline: 1.4494x; 1.4494x over previous
//
#include <hip/hip_runtime.h>

#define DEV __device__ __forceinline__

typedef float f32x4 __attribute__((ext_vector_type(4)));
typedef short short4v __attribute__((ext_vector_type(4)));
typedef short short8v __attribute__((ext_vector_type(8)));
typedef __bf16 bf16x8 __attribute__((ext_vector_type(8)));

DEV unsigned short f2bf(float f) {
  unsigned int u = __float_as_uint(f);
  u += 0x7fffu + ((u >> 16) & 1u);   // round-to-nearest-even
  return (unsigned short)(u >> 16);
}

DEV void async16(void* lds, const void* g) {
  __builtin_amdgcn_global_load_lds((const __attribute__((address_space(1))) void*)g,
                                   (__attribute__((address_space(3))) void*)lds, 16, 0, 0);
}

DEV void store_elem(float* C, long i, float v) { C[i] = v; }
DEV void store_elem(short* C, long i, float v) { C[i] = (short)f2bf(v); }

// ---------------- cast f32 -> bf16 (8 elems/thread) ----------------
__global__ void cast_bf16_kernel(const float* __restrict__ in, short* __restrict__ out) {
  long i = ((long)blockIdx.x * 256 + threadIdx.x) * 8;
  f32x4 a = *(const f32x4*)(in + i);
  f32x4 b = *(const f32x4*)(in + i + 4);
  short8v o;
#pragma unroll
  for (int j = 0; j < 4; ++j) { o[j] = (short)f2bf(a[j]); o[4 + j] = (short)f2bf(b[j]); }
  *(short8v*)(out + i) = o;
}

// ---------------- W [K=1024][N=1024] f32 -> Wt [N][K] bf16 ----------------
__global__ void transpose_cast_kernel(const float* __restrict__ W, short* __restrict__ Wt) {
  __shared__ float t[32][33];
  int n0 = blockIdx.x * 32, k0 = blockIdx.y * 32;
  int tx = threadIdx.x & 31, ty = threadIdx.x >> 5;
#pragma unroll
  for (int r = 0; r < 32; r += 8) t[ty + r][tx] = W[(long)(k0 + ty + r) * 1024 + n0 + tx];
  __syncthreads();
#pragma unroll
  for (int r = 0; r < 32; r += 8)
    Wt[(long)(n0 + ty + r) * 1024 + k0 + tx] = (short)f2bf(t[tx][ty + r]);
}

// ---------------- GEMM: C[M][N] = scale * A[M][K] @ Bt[N][K]^T (+bias) ----------------
// m97 structure: 128x128 tile, BK=32, 4 waves (2x2), 4x4 16x16x32 bf16 MFMA per wave.
// MODE: 0 plain, 1 = only lower+diag 128-tiles (causal scores), 2 = K capped at (bm+1)*128 (PV).
template <typename CT, int MODE>
__global__ __launch_bounds__(256, 2) void gemm_bt(
    const short* __restrict__ A, const short* __restrict__ Bt, CT* __restrict__ C,
    int K, int lda, int ldbt, int ldc,
    long sA, long sBt, long sC,
    const float* __restrict__ bias_m, const float* __restrict__ bias_n, float scale)
{
  const int bn = blockIdx.x, bm = blockIdx.y, bz = blockIdx.z;
  if (MODE == 1 && bn > bm) return;                       // strictly-above-diagonal tile: skip
  const int kend = (MODE == 2) ? min(K, (bm + 1) * 128) : K;

  A += (long)bz * sA;  Bt += (long)bz * sBt;  C += (long)bz * sC;

  __shared__ short As[128 * 32];
  __shared__ short Bs[128 * 32];

  const int tid = threadIdx.x;
  const int wid = tid >> 6, lane = tid & 63;
  const int wm = wid >> 1, wn = wid & 1;
  const int rC = lane >> 2;           // row within 16-row staging chunk
  const int kB = (lane & 3) * 8;      // bf16 col offset within BK=32
  const int fr = lane & 15;
  const int fkB = (lane >> 4) * 16;   // byte offset of this lane's 8-bf16 k-chunk

  const short* Ab = A + (long)bm * 128 * lda;
  const short* Bb = Bt + (long)bn * 128 * ldbt;

  f32x4 acc[4][4] = {};

  for (int kk = 0; kk < kend; kk += 32) {
#pragma unroll
    for (int j = 0; j < 2; ++j) {     // stage A tile: 8 chunks of 16 rows x 32 bf16
      int chunk = j * 4 + wid;
      async16(&As[chunk * 512], Ab + (long)(chunk * 16 + rC) * lda + kk + kB);
    }
#pragma unroll
    for (int j = 0; j < 2; ++j) {     // stage Bt tile
      int chunk = j * 4 + wid;
      async16(&Bs[chunk * 512], Bb + (long)(chunk * 16 + rC) * ldbt + kk + kB);
    }
    __syncthreads();

    bf16x8 af[4], bf_[4];
#pragma unroll
    for (int i = 0; i < 4; ++i)
      af[i] = *(const bf16x8*)((const char*)As + (wm * 64 + i * 16 + fr) * 64 + fkB);
#pragma unroll
    for (int j = 0; j < 4; ++j)
      bf_[j] = *(const bf16x8*)((const char*)Bs + (wn * 64 + j * 16 + fr) * 64 + fkB);
#pragma unroll
    for (int i = 0; i < 4; ++i)
#pragma unroll
      for (int j = 0; j < 4; ++j)
        acc[i][j] = __builtin_amdgcn_mfma_f32_16x16x32_bf16(af[i], bf_[j], acc[i][j], 0, 0, 0);
    __syncthreads();
  }

  const int fq = lane >> 4;
#pragma unroll
  for (int i = 0; i < 4; ++i) {
#pragma unroll
    for (int r = 0; r < 4; ++r) {
      int row = bm * 128 + wm * 64 + i * 16 + fq * 4 + r;
      float bmv = bias_m ? bias_m[row] : 0.f;
#pragma unroll
      for (int j = 0; j < 4; ++j) {
        int col = bn * 128 + wn * 64 + j * 16 + fr;
        float bnv = bias_n ? bias_n[col] : 0.f;
        store_elem(C, (long)row * ldc + col, acc[i][j][r] * scale + bmv + bnv);
      }
    }
  }
}

// ---------------- column softmax (axis = query) over S[bz][q][c], valid q >= c ----------------
// 64-row chunks, fully unrolled register-resident pass: 64 independent loads in
// flight per thread, branch-free masking (also neutralizes poison in never-written
// upper tiles: unwritten => q < c => masked before the max).
__global__ void colstats_partial(const float* __restrict__ S,
                                 float* __restrict__ pmax, float* __restrict__ psum) {
  const int bz = blockIdx.z;
  const int c = blockIdx.x * 256 + threadIdx.x;
  const int q0 = blockIdx.y * 64;
  const long oidx = ((long)bz * 32 + blockIdx.y) * 2048 + c;
  if (q0 + 63 < c) { pmax[oidx] = -1e30f; psum[oidx] = 0.f; return; }  // fully masked
  const float* Sb = S + (long)bz * 4194304 + (long)q0 * 2048 + c;
  float v[64];
#pragma unroll
  for (int i = 0; i < 64; ++i) {
    float t = Sb[(long)i * 2048];
    v[i] = (q0 + i >= c) ? t : -1e30f;
  }
  float m0 = v[0], m1 = v[1], m2 = v[2], m3 = v[3];
#pragma unroll
  for (int i = 4; i < 64; i += 4) {
    m0 = fmaxf(m0, v[i]); m1 = fmaxf(m1, v[i + 1]);
    m2 = fmaxf(m2, v[i + 2]); m3 = fmaxf(m3, v[i + 3]);
  }
  float m = fmaxf(fmaxf(m0, m1), fmaxf(m2, m3));
  float s0 = 0.f, s1 = 0.f, s2 = 0.f, s3 = 0.f;
#pragma unroll
  for (int i = 0; i < 64; i += 4) {
    s0 += __expf(v[i] - m); s1 += __expf(v[i + 1] - m);
    s2 += __expf(v[i + 2] - m); s3 += __expf(v[i + 3] - m);
  }
  pmax[oidx] = m; psum[oidx] = (s0 + s1) + (s2 + s3);
}

__global__ void colstats_combine(const float* __restrict__ pmax, const float* __restrict__ psum,
                                 float* __restrict__ cmax, float* __restrict__ cinv) {
  const int bz = blockIdx.y;
  const int c = blockIdx.x * 256 + threadIdx.x;
  float mv[32];
#pragma unroll
  for (int ch = 0; ch < 32; ++ch) mv[ch] = pmax[((long)bz * 32 + ch) * 2048 + c];
  float M = -1e30f;
#pragma unroll
  for (int ch = 0; ch < 32; ++ch) M = fmaxf(M, mv[ch]);
  float Ssum = 0.f;
#pragma unroll
  for (int ch = 0; ch < 32; ++ch) {
    float s = psum[((long)bz * 32 + ch) * 2048 + c];
    Ssum += (mv[ch] > -1e29f) ? s * __expf(mv[ch] - M) : 0.f;
  }
  cmax[(long)bz * 2048 + c] = M;
  cinv[(long)bz * 2048 + c] = 1.f / Ssum;
}

// P[bz][q][c] = (q>=c) ? exp(S-M[c])*Rinv[c] : 0, bf16.
// Only columns c < climit(q) = ((q>>7)+1)*128 are ever read by the K-capped PV
// GEMM, so skip the dead upper region entirely.
__global__ void sm_normalize(const float* __restrict__ S, const float* __restrict__ cmax,
                             const float* __restrict__ cinv, short* __restrict__ P) {
  const int bz = blockIdx.y;
  const int q = blockIdx.x;
  const int climit = ((q >> 7) + 1) << 7;
  const float* Sr = S + ((long)bz * 2048 + q) * 2048;
  short* Pr = P + ((long)bz * 2048 + q) * 2048;
  const float* Mb = cmax + (long)bz * 2048;
  const float* Rb = cinv + (long)bz * 2048;
  for (int c = threadIdx.x * 4; c < climit; c += 1024) {
    f32x4 sv = *(const f32x4*)(Sr + c);
    f32x4 mv = *(const f32x4*)(Mb + c);
    f32x4 rv = *(const f32x4*)(Rb + c);
    short4v o;
#pragma unroll
    for (int j = 0; j < 4; ++j) {
      float p = (q >= c + j) ? __expf(sv[j] - mv[j]) * rv[j] : 0.f;
      o[j] = (short)f2bf(p);
    }
    *(short4v*)(Pr + c) = o;
  }
}

// ---------------- host side ----------------
extern "C" void kernel_launch(void* const* d_in, const int* in_sizes, int n_in,
                              void* d_out, int out_size, void* d_ws, size_t ws_size,
                              hipStream_t stream) {
  const float* x  = (const float*)d_in[0];
  const float* Wq = (const float*)d_in[1];
  const float* bq = (const float*)d_in[2];
  const float* Wk = (const float*)d_in[3];
  const float* bk = (const float*)d_in[4];
  const float* Wv = (const float*)d_in[5];
  const float* bv = (const float*)d_in[6];
  float* out = (float*)d_out;

  const size_t SZ_XB = 8192ull * 1024 * 2;       // x bf16
  const size_t SZ_WT = 1024ull * 1024 * 2;       // one Wt bf16
  const size_t SZ_QB = SZ_XB;                    // Q / K bf16, Vt bf16
  const size_t N_PMAX = 4ull * 32 * 2048;        // floats (32 chunks of 64 rows)
  const size_t N_CMAX = 4ull * 2048;
  const size_t SZ_STATS = (N_PMAX * 2 + N_CMAX * 2) * 4;
  const size_t SZ_S1 = 2048ull * 2048 * 4;       // one batch of S (f32)
  const size_t SZ_P1 = 2048ull * 2048 * 2;       // one batch of P (bf16)

  char* p = (char*)d_ws;
  short* xb  = (short*)p; p += SZ_XB;
  short* wqt = (short*)p; p += SZ_WT;
  short* wkt = (short*)p; p += SZ_WT;
  short* wvt = (short*)p; p += SZ_WT;
  short* qb  = (short*)p; p += SZ_QB;
  short* kb  = (short*)p; p += SZ_QB;
  short* vt  = (short*)p; p += SZ_QB;
  float* pmax = (float*)p;
  float* psum = pmax + N_PMAX;
  float* cmax = psum + N_PMAX;
  float* cinv = cmax + N_CMAX;
  p += SZ_STATS;
  size_t fixed = (size_t)(p - (char*)d_ws);
  // all-batch S/P if workspace allows, else per-batch reuse (stream-serialized)
  int nbuf = (ws_size >= fixed + 4 * (SZ_S1 + SZ_P1)) ? 4 : 1;
  float* S = (float*)p; p += (size_t)nbuf * SZ_S1;
  short* P = (short*)p;

  // 1) casts / transposes
  cast_bf16_kernel<<<dim3(4096), dim3(256), 0, stream>>>(x, xb);
  transpose_cast_kernel<<<dim3(32, 32), dim3(256), 0, stream>>>(Wq, wqt);
  transpose_cast_kernel<<<dim3(32, 32), dim3(256), 0, stream>>>(Wk, wkt);
  transpose_cast_kernel<<<dim3(32, 32), dim3(256), 0, stream>>>(Wv, wvt);

  // 2) projections (bf16 out, f32 accum + bias)
  // Q[s][d] : A=xb[8192][1024], Bt=Wqt[1024][1024], bias over N(d)
  gemm_bt<short, 0><<<dim3(8, 64, 1), dim3(256), 0, stream>>>(
      xb, wqt, qb, 1024, 1024, 1024, 1024, 0L, 0L, 0L, nullptr, bq, 1.f);
  gemm_bt<short, 0><<<dim3(8, 64, 1), dim3(256), 0, stream>>>(
      xb, wkt, kb, 1024, 1024, 1024, 1024, 0L, 0L, 0L, nullptr, bk, 1.f);
  // Vt[d][s] : A=Wvt[1024][1024], Bt=xb[8192][1024], bias over M(d)
  gemm_bt<short, 0><<<dim3(64, 8, 1), dim3(256), 0, stream>>>(
      wvt, xb, vt, 1024, 1024, 1024, 8192, 0L, 0L, 0L, bv, nullptr, 1.f);

  const long QSTR = 2048L * 1024;   // per-batch Q/K elements
  const long SSTR = 2048L * 2048;   // per-batch S/P elements
  const long OSTR = 2048L * 1024;   // per-batch out elements

  for (int b0 = 0; b0 < 4; b0 += nbuf) {
    // 3) scores: S[q][k] = Q.K^T/32, lower+diag tiles only
    gemm_bt<float, 1><<<dim3(16, 16, nbuf), dim3(256), 0, stream>>>(
        qb + b0 * QSTR, kb + b0 * QSTR, S, 1024, 1024, 1024, 2048,
        QSTR, QSTR, SSTR, nullptr, nullptr, 0.03125f);
    // 4) column softmax over q (valid q >= c)
    colstats_partial<<<dim3(8, 32, nbuf), dim3(256), 0, stream>>>(S, pmax, psum);
    colstats_combine<<<dim3(8, nbuf), dim3(256), 0, stream>>>(pmax, psum, cmax, cinv);
    sm_normalize<<<dim3(2048, nbuf), dim3(256), 0, stream>>>(S, cmax, cinv, P);
    // 5) attn = P @ V : A=P[2048][2048], Bt=Vt[1024][8192] (+b0*2048), K capped per q-tile
    gemm_bt<float, 2><<<dim3(8, 16, nbuf), dim3(256), 0, stream>>>(
        P, vt + b0 * 2048, out + (long)b0 * OSTR, 2048, 2048, 8192, 1024,
        SSTR, 2048L, OSTR, nullptr, nullptr, 1.f);
  }
}

// Round 3
// 227.665 us; speedup vs baseline: 1.6684x; 1.1511x over previous
//
#include <hip/hip_runtime.h>

#define DEV __device__ __forceinline__

typedef float f32x4 __attribute__((ext_vector_type(4)));
typedef short short4v __attribute__((ext_vector_type(4)));
typedef short short8v __attribute__((ext_vector_type(8)));
typedef __bf16 bf16x8 __attribute__((ext_vector_type(8)));

DEV unsigned short f2bf(float f) {
  unsigned int u = __float_as_uint(f);
  u += 0x7fffu + ((u >> 16) & 1u);   // round-to-nearest-even
  return (unsigned short)(u >> 16);
}

DEV void async16(void* lds, const void* g) {
  __builtin_amdgcn_global_load_lds((const __attribute__((address_space(1))) void*)g,
                                   (__attribute__((address_space(3))) void*)lds, 16, 0, 0);
}

DEV void store_elem(float* C, long i, float v) { C[i] = v; }
DEV void store_elem(short* C, long i, float v) { C[i] = (short)f2bf(v); }

// ---------------- cast f32 -> bf16 (8 elems/thread) ----------------
__global__ void cast_bf16_kernel(const float* __restrict__ in, short* __restrict__ out) {
  long i = ((long)blockIdx.x * 256 + threadIdx.x) * 8;
  f32x4 a = *(const f32x4*)(in + i);
  f32x4 b = *(const f32x4*)(in + i + 4);
  short8v o;
#pragma unroll
  for (int j = 0; j < 4; ++j) { o[j] = (short)f2bf(a[j]); o[4 + j] = (short)f2bf(b[j]); }
  *(short8v*)(out + i) = o;
}

// ---------------- W [K=1024][N=1024] f32 -> Wt [N][K] bf16 ----------------
__global__ void transpose_cast_kernel(const float* __restrict__ W, short* __restrict__ Wt) {
  __shared__ float t[32][33];
  int n0 = blockIdx.x * 32, k0 = blockIdx.y * 32;
  int tx = threadIdx.x & 31, ty = threadIdx.x >> 5;
#pragma unroll
  for (int r = 0; r < 32; r += 8) t[ty + r][tx] = W[(long)(k0 + ty + r) * 1024 + n0 + tx];
  __syncthreads();
#pragma unroll
  for (int r = 0; r < 32; r += 8)
    Wt[(long)(n0 + ty + r) * 1024 + k0 + tx] = (short)f2bf(t[tx][ty + r]);
}

__global__ void concat2_kernel(const float* __restrict__ a, const float* __restrict__ b,
                               float* __restrict__ o) {
  int i = blockIdx.x * 256 + threadIdx.x;
  o[i] = (i < 1024) ? a[i] : b[i - 1024];
}

// ---------------- GEMM: C[M][N] = scale * A[M][K] @ Bt[N][K]^T (+bias) ----------------
// 128x128 tile, BK=32, 4 waves (2x2), 4x4 16x16x32 bf16 MFMA per wave.
// Double-buffered LDS + counted vmcnt(4): next tile's loads in flight across MFMA.
// MODE: 0 plain, 1 = lower+diag tiles + fused column-stats epilogue, 2 = K capped.
template <typename CT, int MODE>
__global__ __launch_bounds__(256, 2) void gemm_bt(
    const short* __restrict__ A, const short* __restrict__ Bt, CT* __restrict__ C,
    int K, int lda, int ldbt, int ldc,
    long sA, long sBt, long sC,
    const float* __restrict__ bias_m, const float* __restrict__ bias_n, float scale,
    float* __restrict__ pm_out, float* __restrict__ ps_out)
{
  const int bn = blockIdx.x, bm = blockIdx.y, bz = blockIdx.z;
  if (MODE == 1 && bn > bm) return;
  const int kend = (MODE == 2) ? min(K, (bm + 1) * 128) : K;

  A += (long)bz * sA;  Bt += (long)bz * sBt;  C += (long)bz * sC;

  __shared__ __align__(16) short As[2][128 * 32];
  __shared__ __align__(16) short Bs[2][128 * 32];

  const int tid = threadIdx.x;
  const int wid = tid >> 6, lane = tid & 63;
  const int wm = wid >> 1, wn = wid & 1;
  const int rC = lane >> 2;
  const int kB = (lane & 3) * 8;
  const int fr = lane & 15;
  const int fkB = (lane >> 4) * 16;

  const short* Ab = A + (long)bm * 128 * lda + (long)rC * lda + kB;
  const short* Bb = Bt + (long)bn * 128 * ldbt + (long)rC * ldbt + kB;

  f32x4 acc[4][4] = {};

  auto STAGE = [&](int b, int kk) {
#pragma unroll
    for (int j = 0; j < 2; ++j) {
      int chunk = j * 4 + wid;
      async16(&As[b][chunk * 512], Ab + (long)chunk * 16 * lda + kk);
    }
#pragma unroll
    for (int j = 0; j < 2; ++j) {
      int chunk = j * 4 + wid;
      async16(&Bs[b][chunk * 512], Bb + (long)chunk * 16 * ldbt + kk);
    }
  };

  STAGE(0, 0);
  int cur = 0;
  for (int kk = 0; kk < kend; kk += 32) {
    if (kk + 32 < kend) {
      STAGE(cur ^ 1, kk + 32);
      asm volatile("s_waitcnt vmcnt(4)" ::: "memory");
    } else {
      asm volatile("s_waitcnt vmcnt(0)" ::: "memory");
    }
    __builtin_amdgcn_s_barrier();
    __builtin_amdgcn_sched_barrier(0);

    bf16x8 af[4], bf_[4];
#pragma unroll
    for (int i = 0; i < 4; ++i)
      af[i] = *(const bf16x8*)((const char*)&As[cur][0] + (wm * 64 + i * 16 + fr) * 64 + fkB);
#pragma unroll
    for (int j = 0; j < 4; ++j)
      bf_[j] = *(const bf16x8*)((const char*)&Bs[cur][0] + (wn * 64 + j * 16 + fr) * 64 + fkB);
#pragma unroll
    for (int i = 0; i < 4; ++i)
#pragma unroll
      for (int j = 0; j < 4; ++j)
        acc[i][j] = __builtin_amdgcn_mfma_f32_16x16x32_bf16(af[i], bf_[j], acc[i][j], 0, 0, 0);
    __builtin_amdgcn_s_barrier();
    cur ^= 1;
  }

  const int fq = lane >> 4;
#pragma unroll
  for (int i = 0; i < 4; ++i) {
#pragma unroll
    for (int r = 0; r < 4; ++r) {
      int row = bm * 128 + wm * 64 + i * 16 + fq * 4 + r;
      float bmv = bias_m ? bias_m[row] : 0.f;
#pragma unroll
      for (int j = 0; j < 4; ++j) {
        int col = bn * 128 + wn * 64 + j * 16 + fr;
        float bnv = bias_n ? bias_n[col] : 0.f;
        store_elem(C, (long)row * ldc + col, acc[i][j][r] * scale + bmv + bnv);
      }
    }
  }

  if constexpr (MODE == 1) {
    float* smax = (float*)&As[0][0];   // [2][128]
    float* ssum = smax + 256;
    const int rbase = bm * 128 + wm * 64 + fq * 4;
#pragma unroll
    for (int j = 0; j < 4; ++j) {
      const int col = bn * 128 + wn * 64 + j * 16 + fr;
      float m = -1e30f;
#pragma unroll
      for (int i = 0; i < 4; ++i)
#pragma unroll
        for (int r = 0; r < 4; ++r) {
          int row = rbase + i * 16 + r;
          float v = acc[i][j][r] * scale;
          m = (row >= col) ? fmaxf(m, v) : m;
        }
      m = fmaxf(m, __shfl_xor(m, 16));
      m = fmaxf(m, __shfl_xor(m, 32));
      float s = 0.f;
#pragma unroll
      for (int i = 0; i < 4; ++i)
#pragma unroll
        for (int r = 0; r < 4; ++r) {
          int row = rbase + i * 16 + r;
          float v = acc[i][j][r] * scale;
          s += (row >= col) ? __expf(v - m) : 0.f;
        }
      s += __shfl_xor(s, 16);
      s += __shfl_xor(s, 32);
      if (fq == 0) {
        smax[wm * 128 + wn * 64 + j * 16 + fr] = m;
        ssum[wm * 128 + wn * 64 + j * 16 + fr] = s;
      }
    }
    __syncthreads();
    if (tid < 128) {
      float m0 = smax[tid], m1 = smax[128 + tid];
      float s0 = ssum[tid], s1 = ssum[128 + tid];
      float M = fmaxf(m0, m1);
      float S2 = (m0 > -1e29f ? s0 * __expf(m0 - M) : 0.f)
               + (m1 > -1e29f ? s1 * __expf(m1 - M) : 0.f);
      long o = ((long)bz * 16 + bm) * 2048 + bn * 128 + tid;
      pm_out[o] = M;
      ps_out[o] = S2;
    }
  }
}

// combine 16 row-chunk partials per column; chunks < c/128 were never written.
__global__ void colstats_combine(const float* __restrict__ pmax, const float* __restrict__ psum,
                                 float* __restrict__ cmax, float* __restrict__ cinv) {
  const int bz = blockIdx.y;
  const int c = blockIdx.x * 256 + threadIdx.x;
  const int ch0 = c >> 7;
  float M = -1e30f;
  for (int ch = ch0; ch < 16; ++ch) M = fmaxf(M, pmax[((long)bz * 16 + ch) * 2048 + c]);
  float Ssum = 0.f;
  for (int ch = ch0; ch < 16; ++ch) {
    float m = pmax[((long)bz * 16 + ch) * 2048 + c];
    float s = psum[((long)bz * 16 + ch) * 2048 + c];
    Ssum += (m > -1e29f) ? s * __expf(m - M) : 0.f;
  }
  cmax[(long)bz * 2048 + c] = M;
  cinv[(long)bz * 2048 + c] = 1.f / Ssum;
}

// P = (q>=c) ? exp(S-M[c])*Rinv[c] : 0 (bf16); only c < ((q>>7)+1)*128 is live.
__global__ void sm_normalize(const float* __restrict__ S, const float* __restrict__ cmax,
                             const float* __restrict__ cinv, short* __restrict__ P) {
  const int bz = blockIdx.y;
  const int q = blockIdx.x;
  const int climit = ((q >> 7) + 1) << 7;
  const float* Sr = S + ((long)bz * 2048 + q) * 2048;
  short* Pr = P + ((long)bz * 2048 + q) * 2048;
  const float* Mb = cmax + (long)bz * 2048;
  const float* Rb = cinv + (long)bz * 2048;
  for (int c = threadIdx.x * 4; c < climit; c += 1024) {
    f32x4 sv = *(const f32x4*)(Sr + c);
    f32x4 mv = *(const f32x4*)(Mb + c);
    f32x4 rv = *(const f32x4*)(Rb + c);
    short4v o;
#pragma unroll
    for (int j = 0; j < 4; ++j) {
      float p = (q >= c + j) ? __expf(sv[j] - mv[j]) * rv[j] : 0.f;
      o[j] = (short)f2bf(p);
    }
    *(short4v*)(Pr + c) = o;
  }
}

// ---------------- host side ----------------
extern "C" void kernel_launch(void* const* d_in, const int* in_sizes, int n_in,
                              void* d_out, int out_size, void* d_ws, size_t ws_size,
                              hipStream_t stream) {
  const float* x  = (const float*)d_in[0];
  const float* Wq = (const float*)d_in[1];
  const float* bq = (const float*)d_in[2];
  const float* Wk = (const float*)d_in[3];
  const float* bk = (const float*)d_in[4];
  const float* Wv = (const float*)d_in[5];
  const float* bv = (const float*)d_in[6];
  float* out = (float*)d_out;

  const size_t SZ_XB  = 8192ull * 1024 * 2;
  const size_t SZ_WQK = 2048ull * 1024 * 2;
  const size_t SZ_WT  = 1024ull * 1024 * 2;
  const size_t SZ_QK  = 8192ull * 2048 * 2;
  const size_t SZ_VT  = 1024ull * 8192 * 2;
  const size_t N_PMAX = 4ull * 16 * 2048;
  const size_t N_CMAX = 4ull * 2048;
  const size_t SZ_STATS = (N_PMAX * 2 + N_CMAX * 2 + 2048) * 4;
  const size_t SZ_S1 = 2048ull * 2048 * 4;
  const size_t SZ_P1 = 2048ull * 2048 * 2;

  char* p = (char*)d_ws;
  short* xb   = (short*)p; p += SZ_XB;
  short* wqkt = (short*)p; p += SZ_WQK;
  short* wvt  = (short*)p; p += SZ_WT;
  short* qkb  = (short*)p; p += SZ_QK;
  short* vt   = (short*)p; p += SZ_VT;
  float* pmax = (float*)p;
  float* psum = pmax + N_PMAX;
  float* cmax = psum + N_PMAX;
  float* cinv = cmax + N_CMAX;
  float* bqk  = cinv + N_CMAX;
  p += SZ_STATS;
  size_t fixed = (size_t)(p - (char*)d_ws);
  int nbuf = (ws_size >= fixed + 4 * (SZ_S1 + SZ_P1)) ? 4 : 1;
  float* S = (float*)p; p += (size_t)nbuf * SZ_S1;
  short* P = (short*)p;

  cast_bf16_kernel<<<dim3(4096), dim3(256), 0, stream>>>(x, xb);
  transpose_cast_kernel<<<dim3(32, 32), dim3(256), 0, stream>>>(Wq, wqkt);
  transpose_cast_kernel<<<dim3(32, 32), dim3(256), 0, stream>>>(Wk, wqkt + 1024 * 1024);
  transpose_cast_kernel<<<dim3(32, 32), dim3(256), 0, stream>>>(Wv, wvt);
  concat2_kernel<<<dim3(8), dim3(256), 0, stream>>>(bq, bk, bqk);

  // QK fused projection: C[8192][2048] = xb @ [Wq;Wk]^T + [bq;bk]
  gemm_bt<short, 0><<<dim3(16, 64, 1), dim3(256), 0, stream>>>(
      xb, wqkt, qkb, 1024, 1024, 1024, 2048, 0L, 0L, 0L, nullptr, bqk, 1.f,
      nullptr, nullptr);
  // Vt[d][s]
  gemm_bt<short, 0><<<dim3(64, 8, 1), dim3(256), 0, stream>>>(
      wvt, xb, vt, 1024, 1024, 1024, 8192, 0L, 0L, 0L, bv, nullptr, 1.f,
      nullptr, nullptr);

  const long QKSTR = 2048L * 2048;
  const long SSTR  = 2048L * 2048;
  const long OSTR  = 2048L * 1024;

  for (int b0 = 0; b0 < 4; b0 += nbuf) {
    gemm_bt<float, 1><<<dim3(16, 16, nbuf), dim3(256), 0, stream>>>(
        qkb + (long)b0 * QKSTR, qkb + (long)b0 * QKSTR + 1024, S,
        1024, 2048, 2048, 2048, QKSTR, QKSTR, SSTR,
        nullptr, nullptr, 0.03125f, pmax, psum);
    colstats_combine<<<dim3(8, nbuf), dim3(256), 0, stream>>>(pmax, psum, cmax, cinv);
    sm_normalize<<<dim3(2048, nbuf), dim3(256), 0, stream>>>(S, cmax, cinv, P);
    gemm_bt<float, 2><<<dim3(8, 16, nbuf), dim3(256), 0, stream>>>(
        P, vt + b0 * 2048, out + (long)b0 * OSTR, 2048, 2048, 8192, 1024,
        SSTR, 2048L, OSTR, nullptr, nullptr, 1.f, nullptr, nullptr);
  }
}